// Round 6
// baseline (17948.718 us; speedup 1.0000x reference)
//
#include <hip/hip_runtime.h>
#include <cmath>

constexpr int kB = 64, kS = 512, kD = 128, kH = 512, kOut = 24;
constexpr int kBlocks = 256, kThreads = 512;   // grid<=256: proven coop-launchable
constexpr size_t kBarOffBytes = (size_t)5 * kB * kH * 4;   // after H0,H1,tmp1

struct Params {
  const float* x;
  const float* w0[4]; const float* b0[4];   // f,i,o,g  [512,640] / [512]
  const float* w1[4]; const float* b1[4];   // f,i,o,g  [512,1024] / [512]
  const float* fc1w; const float* fc1b;
  const float* fc2w; const float* fc2b;
  float* H0;    // 2 buffers [64][512]
  float* H1;    // 2 buffers [64][512]
  float* tmp1;  // [64][512]
  unsigned* bar; // word layout: dom slots [0,4096), dom gen @4096+d*16,
                 //              full slots [4224,8320), full gen @8320
  float* out;   // [64][24]
};

__device__ __forceinline__ float sigmoidf_(float v) {
  return 1.0f / (1.0f + expf(-v));
}

// Store-based group barrier (parallel slot stores, no RMW serialization).
// Leader polls all n slots with n lanes + __syncthreads_and. Monotone.
// (round-4 verified)
__device__ __forceinline__ void sync_group(unsigned* slots, unsigned* gen,
                                           int myIdx, int n, bool leader,
                                           unsigned r) {
  const int tid = threadIdx.x;
  __syncthreads();
  if (leader) {
    if (tid == 0) {
      __threadfence();
      __hip_atomic_store(slots + myIdx * 16, r + 1, __ATOMIC_RELAXED,
                         __HIP_MEMORY_SCOPE_AGENT);
    }
    unsigned* ps = slots + (tid < n ? tid : 0) * 16;
    for (;;) {
      unsigned v = __hip_atomic_load(ps, __ATOMIC_RELAXED,
                                     __HIP_MEMORY_SCOPE_AGENT);
      if (__syncthreads_and((tid < n) ? (int)(v > r) : 1)) break;
      __builtin_amdgcn_s_sleep(1);
    }
    __threadfence();
    if (tid == 0)
      __hip_atomic_store(gen, r + 1, __ATOMIC_RELAXED,
                         __HIP_MEMORY_SCOPE_AGENT);
    __syncthreads();
  } else {
    if (tid == 0) {
      __threadfence();
      __hip_atomic_store(slots + myIdx * 16, r + 1, __ATOMIC_RELAXED,
                         __HIP_MEMORY_SCOPE_AGENT);
      while (__hip_atomic_load(gen, __ATOMIC_RELAXED,
                               __HIP_MEMORY_SCOPE_AGENT) <= r)
        __builtin_amdgcn_s_sleep(1);
      __threadfence();
    }
    __syncthreads();
  }
}

// Block (cgi, bh): cgi=bid>>1 owns hidden cols j0..j0+3 (16 gate-rows),
// bh=bid&1 owns batches bbase..+31.
// ROUND-6 RESTRUCTURE (round-5 evidence: doubling waves didn't help -> stalls
// are global barriers, not per-wave latency):
//   wave w (tid>>6) owns batches bbase+4w..+3.  lane = kt(0..15)*4 + r4(0..3).
//   Each wave SELF-STAGES its own 4 batches' u into its private LDS arena ->
//   the whole k-loop is wave-local: ZERO __syncthreads in it, and no
//   vmcnt(0)-before-barrier drain defeating the global prefetch.
//   Thread computes acc[4 gate-rows of its gate r4][4 wave batches] over its
//   kt k-slice; k-reduction = 16 in-wave partials -> wave-private LDS ->
//   one sync -> 512-thread reduce -> one sync -> activation.
//   Per step: 4 __syncthreads + 1 grid barrier (was ~21 + 1).
__global__ void __launch_bounds__(kThreads, 2)
lstm_persistent(Params p) {
  __shared__ float wlds0[16 * 644];    // 41.2 KB  w0 slice (row stride 644)
  __shared__ float wlds1[16 * 1028];   // 65.8 KB  w1 slice (row stride 1028)
  __shared__ float arena[8][1066];     // 34.1 KB  per-wave: u dbuf [2][4][132]
                                       //          unions with partials [16][66]
  __shared__ float gs[512];            // gate preacts [gaterow(16)][b(32)]

  const int tid = threadIdx.x;
  const int bid = blockIdx.x;
  const int cgi = bid >> 1;
  const int bh  = bid & 1;
  const int j0  = cgi * 4;
  const int bbase = bh * 32;

  const int wv_ = tid >> 6;            // wave 0..7: owns batches 4*wv_..+3
  const int l   = tid & 63;
  const int kt  = l >> 2;              // 0..15  k-split
  const int r4  = l & 3;               // gate (broadcast dim for u reads)

  // staging map: lane stages quads quad_s and quad_s+16 of batch-row row_s
  const int row_s  = l >> 4;           // 0..3 (wave-local batch)
  const int quad_s = l & 15;           // 0..15
  const int bS = bbase + 4 * wv_ + row_s;   // global batch staged by this lane
  float* const uw = &arena[wv_][0];

  unsigned rnd = 0;

  // one-time: weight slice -> LDS (padded strides for bank spread)
  for (int idx = tid; idx < 16 * 160; idx += kThreads) {   // w0: 16 x 160 f4
    const int row = idx / 160;
    const int k4  = idx - row * 160;
    const float4 v =
        *(const float4*)(p.w0[row >> 2] + (j0 + (row & 3)) * 640 + k4 * 4);
    *(float4*)(wlds0 + row * 644 + k4 * 4) = v;
  }
  for (int idx = tid; idx < 16 * 256; idx += kThreads) {   // w1: 16 x 256 f4
    const int row = idx >> 8;
    const int k4  = idx & 255;
    const float4 v =
        *(const float4*)(p.w1[row >> 2] + (j0 + (row & 3)) * 1024 + k4 * 4);
    *(float4*)(wlds1 + row * 1028 + k4 * 4) = v;
  }

  // zero-init buffers read at t=0 (buffer index 1)
  if (tid < 128) {
    const int jl = tid >> 5, bb = tid & 31;
    const int b = bbase + bb;
    p.H0[kB * kH + b * kH + j0 + jl] = 0.f;
    p.H1[kB * kH + b * kH + j0 + jl] = 0.f;
  }

  float* H0buf[2] = { p.H0, p.H0 + kB * kH };
  float* H1buf[2] = { p.H1, p.H1 + kB * kH };
  float c0 = 0.f, c1 = 0.f;

  unsigned* domSlots = p.bar + bh * 2048;
  unsigned* domGen   = p.bar + 4096 + bh * 16;
  const bool leader  = (cgi == 0);

  sync_group(domSlots, domGen, cgi, 128, leader, rnd); rnd++;

  // Phase: C chunks of 128 k. Weights from LDS; u self-staged per wave into
  // its private arena (dbuf by chunk parity). NO intra-k-loop syncs.
  auto runPhase = [&](int C, auto&& src, const float* __restrict__ wl,
                      int wstride, const float* const* Bv, float& cs,
                      float* __restrict__ hout) {
    float acc[4][4];
    #pragma unroll
    for (int a = 0; a < 4; ++a)
      #pragma unroll
      for (int q = 0; q < 4; ++q) acc[a][q] = 0.f;

    const float* wr[4];
    #pragma unroll
    for (int rr = 0; rr < 4; ++rr) wr[rr] = wl + (r4 * 4 + rr) * wstride;

    auto compute = [&](int c, const float* __restrict__ ub) {
      #pragma unroll
      for (int m = 0; m < 2; ++m) {
        const int q4 = (m * 16 + kt) * 4;
        float4 wvv[4], uv[4];
        #pragma unroll
        for (int rr = 0; rr < 4; ++rr)
          wvv[rr] = *(const float4*)(wr[rr] + c * 128 + q4);
        #pragma unroll
        for (int b = 0; b < 4; ++b)
          uv[b] = *(const float4*)(ub + b * 132 + q4);   // 4-way r4 broadcast
        #pragma unroll
        for (int rr = 0; rr < 4; ++rr)
          #pragma unroll
          for (int b = 0; b < 4; ++b) {
            acc[rr][b] = fmaf(wvv[rr].x, uv[b].x, acc[rr][b]);
            acc[rr][b] = fmaf(wvv[rr].y, uv[b].y, acc[rr][b]);
            acc[rr][b] = fmaf(wvv[rr].z, uv[b].z, acc[rr][b]);
            acc[rr][b] = fmaf(wvv[rr].w, uv[b].w, acc[rr][b]);
          }
      }
    };

    // sA = even chunks, sB = odd chunks (static names -> no spills)
    float4 sA0 = *(const float4*)src(0, bS, quad_s);
    float4 sA1 = *(const float4*)src(0, bS, quad_s + 16);
    float4 sB0, sB1;
    *(float4*)(uw + row_s * 132 + quad_s * 4) = sA0;
    *(float4*)(uw + row_s * 132 + (quad_s + 16) * 4) = sA1;
    // no barrier: wave reads only its own staged region (lgkmcnt-ordered)

    for (int cc = 0; cc < C; cc += 2) {
      { // even chunk c = cc  (buf 0)
        const int c = cc;
        if (c + 1 < C) {
          sB0 = *(const float4*)src(c + 1, bS, quad_s);
          sB1 = *(const float4*)src(c + 1, bS, quad_s + 16);
        }
        compute(c, uw);
        if (c + 1 < C) {
          *(float4*)(uw + 528 + row_s * 132 + quad_s * 4) = sB0;
          *(float4*)(uw + 528 + row_s * 132 + (quad_s + 16) * 4) = sB1;
        }
      }
      if (cc + 1 < C) { // odd chunk c = cc+1  (buf 1)
        const int c = cc + 1;
        if (c + 1 < C) {
          sA0 = *(const float4*)src(c + 1, bS, quad_s);
          sA1 = *(const float4*)src(c + 1, bS, quad_s + 16);
        }
        compute(c, uw + 528);
        if (c + 1 < C) {
          *(float4*)(uw + row_s * 132 + quad_s * 4) = sA0;
          *(float4*)(uw + row_s * 132 + (quad_s + 16) * 4) = sA1;
        }
      }
    }

    // in-wave k partials -> wave-private LDS (unions with dead u region)
    #pragma unroll
    for (int rr = 0; rr < 4; ++rr) {
      float4 pv = { acc[rr][0], acc[rr][1], acc[rr][2], acc[rr][3] };
      *(float4*)(uw + kt * 66 + (r4 * 4 + rr) * 4) = pv;
    }
    __syncthreads();                         // sync1: partials visible
    {
      const int rIdx = tid >> 5, bb = tid & 31;
      const float* pw = &arena[bb >> 2][0];
      float s = 0.f;
      #pragma unroll
      for (int q = 0; q < 16; ++q) s += pw[q * 66 + rIdx * 4 + (bb & 3)];
      s += Bv[rIdx >> 2][j0 + (rIdx & 3)];
      gs[tid] = s;
    }
    __syncthreads();                         // sync2: gs visible
    if (tid < 128) {
      const int jl = tid >> 5, bb = tid & 31;
      const int b = bbase + bb;
      const float fg = sigmoidf_(gs[(0 + jl) * 32 + bb]);
      const float ig = sigmoidf_(gs[(4 + jl) * 32 + bb]);
      const float og = sigmoidf_(gs[(8 + jl) * 32 + bb]);
      const float gg = tanhf(gs[(12 + jl) * 32 + bb]);
      cs = fg * cs + ig * gg;
      hout[b * kH + j0 + jl] = og * tanhf(cs);
    }
    // safe: next phase staging starts only in waves that passed sync2, and
    // its gs write comes after its own sync1 (a barrier all threads reach).
  };

  // ---------- fused sequence: 1 domain barrier per step ----------
  {
    const float* __restrict__ h0prev = H0buf[1];
    auto srcA = [&](int c, int b, int k4) {
      return (c == 0) ? p.x + (b * kS + 0) * kD + k4 * 4
                      : h0prev + b * kH + (c - 1) * 128 + k4 * 4;
    };
    runPhase(5, srcA, wlds0, 644, p.b0, c0, H0buf[0]);
  }
  sync_group(domSlots, domGen, cgi, 128, leader, rnd); rnd++;

  for (int t = 0; t < kS; ++t) {
    {
      const float* __restrict__ h0cur  = H0buf[t & 1];
      const float* __restrict__ h1prev = H1buf[(t + 1) & 1];
      auto srcB = [&](int c, int b, int k4) {
        return (c < 4) ? h0cur + b * kH + c * 128 + k4 * 4
                       : h1prev + b * kH + (c - 4) * 128 + k4 * 4;
      };
      runPhase(8, srcB, wlds1, 1028, p.b1, c1, H1buf[t & 1]);
    }
    if (t < kS - 1) {
      const int tn = t + 1;
      const float* __restrict__ h0prev = H0buf[t & 1];
      auto srcA = [&](int c, int b, int k4) {
        return (c == 0) ? p.x + (b * kS + tn) * kD + k4 * 4
                        : h0prev + b * kH + (c - 1) * 128 + k4 * 4;
      };
      runPhase(5, srcA, wlds0, 644, p.b0, c0, H0buf[(t + 1) & 1]);
    }
    sync_group(domSlots, domGen, cgi, 128, leader, rnd); rnd++;
  }

  // ---------- head: fc1 -> (FULL barrier) -> fc2 -> relu ----------
  const float* h1f = H1buf[(kS - 1) & 1];
  if (tid < 128) {
    const int jl = tid >> 5, bb = tid & 31;
    const int b = bbase + bb;
    const float* __restrict__ wrr = p.fc1w + (j0 + jl) * kH;
    const float* __restrict__ hr = h1f + b * kH;
    float s = p.fc1b[j0 + jl];
    for (int k = 0; k < kH; k += 4) {
      const float4 wv4 = *(const float4*)(wrr + k);
      const float4 hv = *(const float4*)(hr + k);
      s = fmaf(wv4.x, hv.x, s); s = fmaf(wv4.y, hv.y, s);
      s = fmaf(wv4.z, hv.z, s); s = fmaf(wv4.w, hv.w, s);
    }
    p.tmp1[b * kH + j0 + jl] = s;
  }
  // fc2 reads tmp1 across BOTH domains -> one full-grid barrier
  sync_group(p.bar + 4224, p.bar + 8320, bid, 256, bid == 0, 0u);

  if (bid < kOut && tid < kB) {
    const int b = tid;
    const float* __restrict__ wrr = p.fc2w + bid * kH;
    const float* __restrict__ tr = p.tmp1 + b * kH;
    float s = p.fc2b[bid];
    for (int k = 0; k < kH; k += 4) {
      const float4 wv4 = *(const float4*)(wrr + k);
      const float4 tv = *(const float4*)(tr + k);
      s = fmaf(wv4.x, tv.x, s); s = fmaf(wv4.y, tv.y, s);
      s = fmaf(wv4.z, tv.z, s); s = fmaf(wv4.w, tv.w, s);
    }
    p.out[b * kOut + bid] = fmaxf(s, 0.f);
  }
}

extern "C" void kernel_launch(void* const* d_in, const int* in_sizes, int n_in,
                              void* d_out, int out_size, void* d_ws, size_t ws_size,
                              hipStream_t stream) {
  (void)in_sizes; (void)n_in; (void)out_size; (void)ws_size;
  Params p;
  p.x = (const float*)d_in[0];
  p.w0[0] = (const float*)d_in[1];  p.b0[0] = (const float*)d_in[2];
  p.w0[1] = (const float*)d_in[3];  p.b0[1] = (const float*)d_in[4];
  p.w0[2] = (const float*)d_in[5];  p.b0[2] = (const float*)d_in[6];
  p.w0[3] = (const float*)d_in[7];  p.b0[3] = (const float*)d_in[8];
  p.w1[0] = (const float*)d_in[9];  p.b1[0] = (const float*)d_in[10];
  p.w1[1] = (const float*)d_in[11]; p.b1[1] = (const float*)d_in[12];
  p.w1[2] = (const float*)d_in[13]; p.b1[2] = (const float*)d_in[14];
  p.w1[3] = (const float*)d_in[15]; p.b1[3] = (const float*)d_in[16];
  p.fc1w = (const float*)d_in[17];  p.fc1b = (const float*)d_in[18];
  p.fc2w = (const float*)d_in[19];  p.fc2b = (const float*)d_in[20];

  float* ws = (float*)d_ws;
  p.H0   = ws;                       // 2 * 64*512
  p.H1   = ws + 2 * kB * kH;         // 2 * 64*512
  p.tmp1 = ws + 4 * kB * kH;         // 64*512
  p.bar  = (unsigned*)((char*)d_ws + kBarOffBytes);
  p.out  = (float*)d_out;

  // barrier state must start at 0 (ws is poisoned 0xAA before every launch)
  hipMemsetAsync((char*)d_ws + kBarOffBytes, 0, 36864, stream);

  void* args[] = { &p };
  hipLaunchCooperativeKernel(reinterpret_cast<const void*>(&lstm_persistent),
                             dim3(kBlocks), dim3(kThreads), args, 0, stream);
}